// Round 12
// baseline (127.757 us; speedup 1.0000x reference)
//
#include <hip/hip_runtime.h>
#include <math.h>

#define MM 16
#define CC 345
#define MC (MM*CC)   // 5520
#define KTOP 4
#define GAP_THR 1e-5f
#define NT 256       // 4 waves/block, one row b per BLOCK, 4 m-rows per wave
#define PS 348       // padded partial stride

__device__ __forceinline__ float fexp(float x) { return __expf(x); }
__device__ __forceinline__ float flog(float x) { return __logf(x); }

__device__ __forceinline__ float rmax16(float v) {
    #pragma unroll
    for (int off = 8; off; off >>= 1) v = fmaxf(v, __shfl_xor(v, off, 16));
    return v;
}
__device__ __forceinline__ float rmin16(float v) {
    #pragma unroll
    for (int off = 8; off; off >>= 1) v = fminf(v, __shfl_xor(v, off, 16));
    return v;
}
__device__ __forceinline__ float rsum16(float v) {
    #pragma unroll
    for (int off = 8; off; off >>= 1) v += __shfl_xor(v, off, 16);
    return v;
}
__device__ __forceinline__ float rmax64(float v) {
    #pragma unroll
    for (int off = 32; off; off >>= 1) v = fmaxf(v, __shfl_xor(v, off, 64));
    return v;
}
__device__ __forceinline__ float rsum64(float v) {
    #pragma unroll
    for (int off = 32; off; off >>= 1) v += __shfl_xor(v, off, 64);
    return v;
}

__global__ __launch_bounds__(NT)
void ens_main(const float* __restrict__ y, const int* __restrict__ labels,
              float* __restrict__ out, float* __restrict__ partial, int B)
{
    const int tid = threadIdx.x;
    const int w   = tid >> 6;     // wave 0..3, owns m = 4w..4w+3
    const int l   = tid & 63;
    const int b   = blockIdx.x;
    const int lm  = l & 15;       // lane's "m" role in phase 3
    const int mq  = l >> 4;       // 16-lane group id 0..3 (guard path)
    const int g   = l & 15;

    __shared__ float s_truep[MM], s_epl[MM], s_mx[MM];
    __shared__ float s_pa[4][PS];     // ems partials per wave
    __shared__ float s_pp[4][PS];     // ems_post partials per wave
    __shared__ float s_sems[CC];
    __shared__ float s_red[4], s_red2[4];

    const int label = labels[b];
    const float* yb = y + (size_t)b * MC;

    // ---- Phase 1+2 fused (barrier-free): wave w loads its 4 rows into
    // registers (24 VGPR) and computes softmax stats from registers.
    float d[4][6];
    #pragma unroll
    for (int i = 0; i < 4; ++i) {
        const float* row = yb + (4 * w + i) * CC;
        #pragma unroll
        for (int r = 0; r < 5; ++r) d[i][r] = row[l + (r << 6)];
        d[i][5] = (l < 25) ? row[320 + l] : 0.f;
    }
    #pragma unroll
    for (int i = 0; i < 4; ++i) {
        const int m = 4 * w + i;
        // fmax associative/commutative -> mx bit-identical to all prior rounds
        float mx = fmaxf(fmaxf(fmaxf(d[i][0], d[i][1]), fmaxf(d[i][2], d[i][3])), d[i][4]);
        mx = fmaxf(mx, (l < 25) ? d[i][5] : -INFINITY);
        mx = rmax64(mx);
        float se = fexp(d[i][0] - mx) + fexp(d[i][1] - mx) + fexp(d[i][2] - mx)
                 + fexp(d[i][3] - mx) + fexp(d[i][4] - mx);
        se += (l < 25) ? fexp(d[i][5] - mx) : 0.f;
        se = rsum64(se);
        if (l == 0) {
            const float lt = yb[m * CC + label];
            s_mx[m]    = mx;
            s_truep[m] = fexp(lt - mx) / se;          // fast probs[b,m,label]
            s_epl[m]   = -(lt - mx - flog(se));       // -log_softmax[b,m,label]
        }
    }
    __syncthreads();   // #1

    // ---- Phase 3a (verbatim logic; all 4 waves redundantly):
    const float tpv  = s_truep[lm];
    const float eplv = s_epl[lm];
    float mxs = rmax16(tpv);
    float e0  = fexp(tpv - mxs);
    float tc  = e0 / rsum16(e0);                       // true_confs (fast)
    float s1  = fmaxf(rsum16(fabsf(tc)), 1e-12f);
    float wm  = tc / s1;                               // weighted_mat
    int rank = 0;
    #pragma unroll
    for (int j = 0; j < MM; ++j) {
        const float vj = __shfl(tc, j, 16);
        rank += (vj > tc) || (vj == tc && j < lm);
    }
    bool sel = (rank < KTOP);
    const float val4 = rmin16(sel ? tc : INFINITY);    // smallest selected
    const float val5 = rmax16(sel ? -INFINITY : tc);   // largest unselected
    const bool need = (val4 - val5 < GAP_THR);         // wave-uniform

    // ---- Phase 3b (verbatim): guarded rows -> BIT-EXACT round-1 chain:
    // libm expf, strided-16 ascending global reads + xor-tree rsum16 (same
    // exact mx), serial ascending denominator, tie-ranked top-4.
    if (need) {
        float tpp4[4];
        #pragma unroll
        for (int i = 0; i < 4; ++i) {
            const int m = i * 4 + mq;
            const float* row = yb + m * CC;
            const float mx = s_mx[m];                  // bitwise-same as phase 2
            float se = 0.f;
            for (int c = g; c < CC; c += 16) se += expf(row[c] - mx);
            se = rsum16(se);
            tpp4[i] = expf(row[label] - mx) / se;
        }
        float tppv = 0.f;
        {
            const int src = (lm & 3) << 4;
            #pragma unroll
            for (int i = 0; i < 4; ++i) {
                const float a_ = __shfl(tpp4[i], src, 64);
                if ((lm >> 2) == i) tppv = a_;
            }
        }
        const float mxx = rmax16(tppv);
        const float ev  = expf(tppv - mxx);
        float ses = 0.f;
        #pragma unroll
        for (int m = 0; m < MM; ++m) ses += __shfl(ev, m, 16);  // serial ascending
        const float tcpv = ev / ses;
        int rk = 0;
        #pragma unroll
        for (int j = 0; j < MM; ++j) {
            const float vj = __shfl(tcpv, j, 16);
            rk += (vj > tcpv) || (vj == tcpv && j < lm);
        }
        sel = (rk < KTOP);
    }

    // ---- Phase 3c (verbatim): finish per-b math
    const float post = sel ? tc : 0.f;
    const float psum = fmaxf(rsum16(fabsf(post)), 1e-12f);
    const float pw   = post / psum;
    const float mw = rmax16(wm);
    const float ex = fexp(wm - mw);
    const float xv = ex / rsum16(ex);
    const float mt = rmax16(tc);
    const float et = fexp(tc - mt);
    const float tv = et / rsum16(et);
    const float childp = eplv * xv;
    const float confp  = fmaxf(xv, 0.f) - xv * tv + flog(1.f + fexp(-fabsf(xv)));
    const float childs = rsum16(childp);
    const float confs  = rsum16(confp);
    if (tid == 0) {
        partial[(size_t)b * 3 + 0] = childs;
        partial[(size_t)b * 3 + 1] = confs;
    }
    if (tid < MM) {
        const size_t off_wm = (size_t)B * CC + 3;
        const size_t off_tc = off_wm + (size_t)B * MM;
        out[off_wm + (size_t)b * MM + tid] = xv;  // wm_soft
        out[off_tc + (size_t)b * MM + tid] = tc;  // true_confs
    }

    // ---- Phase 4: per-wave partial einsum over its 4 rows, from registers.
    float pa[6], pp[6];
    #pragma unroll
    for (int r = 0; r < 6; ++r) { pa[r] = 0.f; pp[r] = 0.f; }
    #pragma unroll
    for (int i = 0; i < 4; ++i) {
        const int m = 4 * w + i;                   // 0..15
        const float wvm = __shfl(wm, m, 16);       // group-local src, all groups identical
        const float pvm = __shfl(pw, m, 16);
        #pragma unroll
        for (int r = 0; r < 6; ++r) {
            pa[r] = fmaf(d[i][r], wvm, pa[r]);
            pp[r] = fmaf(d[i][r], pvm, pp[r]);
        }
    }
    #pragma unroll
    for (int r = 0; r < 5; ++r) {
        s_pa[w][l + (r << 6)] = pa[r];
        s_pp[w][l + (r << 6)] = pp[r];
    }
    if (l < 25) { s_pa[w][320 + l] = pa[5]; s_pp[w][320 + l] = pp[5]; }
    __syncthreads();   // #2

    // ---- Phase 4b: combine partials (ascending w = ascending m blocks),
    // write ems_out_post, stash ems for phase 5.
    float a0 = -INFINITY, a1 = -INFINITY;
    {
        int c = tid;
        if (c < CC) {
            float a  = s_pa[0][c]; a  += s_pa[1][c]; a  += s_pa[2][c]; a  += s_pa[3][c];
            float ap = s_pp[0][c]; ap += s_pp[1][c]; ap += s_pp[2][c]; ap += s_pp[3][c];
            out[(size_t)b * CC + c] = ap;
            s_sems[c] = a;
            a0 = a;
        }
        c = tid + NT;
        if (c < CC) {
            float a  = s_pa[0][c]; a  += s_pa[1][c]; a  += s_pa[2][c]; a  += s_pa[3][c];
            float ap = s_pp[0][c]; ap += s_pp[1][c]; ap += s_pp[2][c]; ap += s_pp[3][c];
            out[(size_t)b * CC + c] = ap;
            s_sems[c] = a;
            a1 = a;
        }
    }

    // ---- Phase 5: -log_softmax(ems_out)[label]
    float mx5 = rmax64(fmaxf(a0, a1));
    if (l == 0) s_red[w] = mx5;
    __syncthreads();   // #3
    const float bmax = fmaxf(fmaxf(s_red[0], s_red[1]), fmaxf(s_red[2], s_red[3]));
    float e5 = 0.f;
    if (tid < CC)      e5 += fexp(a0 - bmax);
    if (tid + NT < CC) e5 += fexp(a1 - bmax);
    e5 = rsum64(e5);
    if (l == 0) s_red2[w] = e5;
    __syncthreads();   // #4
    if (tid == 0) {
        const float s = ((s_red2[0] + s_red2[1]) + s_red2[2]) + s_red2[3];
        partial[(size_t)b * 3 + 2] = -(s_sems[label] - bmax - flog(s));
    }
}

// Two-stage deterministic reduction of per-b partials -> the 3 scalar losses.
__global__ __launch_bounds__(64)
void ens_reduce1(const float* __restrict__ partial, double* __restrict__ ws2, int B)
{
    const int t  = threadIdx.x;     // 0..63
    const int i  = blockIdx.x;      // 0..63
    const int r0 = i * 128 + t * 2;
    double c = 0.0, f = 0.0, e = 0.0;
    #pragma unroll
    for (int k = 0; k < 2; ++k) {
        const int r = r0 + k;
        c += (double)partial[(size_t)r * 3 + 0];
        f += (double)partial[(size_t)r * 3 + 1];
        e += (double)partial[(size_t)r * 3 + 2];
    }
    #pragma unroll
    for (int off = 32; off; off >>= 1) {
        c += __shfl_xor(c, off);
        f += __shfl_xor(f, off);
        e += __shfl_xor(e, off);
    }
    if (t == 0) {
        ws2[(size_t)i * 3 + 0] = c;
        ws2[(size_t)i * 3 + 1] = f;
        ws2[(size_t)i * 3 + 2] = e;
    }
}

__global__ __launch_bounds__(64)
void ens_reduce2(const double* __restrict__ ws2, float* __restrict__ out, int B)
{
    const int t = threadIdx.x;
    double c = ws2[(size_t)t * 3 + 0];
    double f = ws2[(size_t)t * 3 + 1];
    double e = ws2[(size_t)t * 3 + 2];
    #pragma unroll
    for (int off = 32; off; off >>= 1) {
        c += __shfl_xor(c, off);
        f += __shfl_xor(f, off);
        e += __shfl_xor(e, off);
    }
    if (t == 0) {
        const size_t base = (size_t)B * CC;
        out[base + 0] = (float)(c / (double)((size_t)B * MM));  // child_loss
        out[base + 1] = (float)(f / (double)((size_t)B * MM));  // confidence_loss
        out[base + 2] = (float)(e / (double)B);                 // ensemble_loss
    }
}

extern "C" void kernel_launch(void* const* d_in, const int* in_sizes, int n_in,
                              void* d_out, int out_size, void* d_ws, size_t ws_size,
                              hipStream_t stream)
{
    const float* y      = (const float*)d_in[0];
    const int*   labels = (const int*)d_in[1];
    const int    B      = in_sizes[1];      // 8192
    float* out     = (float*)d_out;
    float* partial = (float*)d_ws;                       // B*3 floats
    double* ws2    = (double*)((char*)d_ws + (((size_t)B * 3 * sizeof(float) + 255) & ~(size_t)255));

    ens_main<<<dim3(B), dim3(NT), 0, stream>>>(y, labels, out, partial, B);
    ens_reduce1<<<dim3(64), dim3(64), 0, stream>>>(partial, ws2, B);
    ens_reduce2<<<dim3(1), dim3(64), 0, stream>>>(ws2, out, B);
}

// Round 15
// 73.203 us; speedup vs baseline: 1.7453x; 1.7453x over previous
//
#include <hip/hip_runtime.h>
#include <math.h>

#define MM 16
#define CC 345
#define MC (MM*CC)   // 5520
#define KTOP 4
// Guard threshold in tc-space. Covers (a) fast-exp vs libm perturbation of a
// tc gap (~2e-8 abs: numerator-only, denominator common-mode) and (b) the
// float-rounding tie-collapse window (~1 ulp of tc ~ 7.5e-9) with >=10x
// margin. At 3e-7 the guard fires on ~0.5% of rows (was ~20-30% at 1e-5,
// which made the libm guard pass ~85% of all kernel VALU work).
#define GAP_THR 3e-7f
#define NT 512

__device__ __forceinline__ float fexp(float x) { return __expf(x); }
__device__ __forceinline__ float flog(float x) { return __logf(x); }

// width-16 reductions over a 16-lane group
__device__ __forceinline__ float rmax16(float v) {
    #pragma unroll
    for (int off = 8; off; off >>= 1) v = fmaxf(v, __shfl_xor(v, off, 16));
    return v;
}
__device__ __forceinline__ float rmin16(float v) {
    #pragma unroll
    for (int off = 8; off; off >>= 1) v = fminf(v, __shfl_xor(v, off, 16));
    return v;
}
__device__ __forceinline__ float rsum16(float v) {
    #pragma unroll
    for (int off = 8; off; off >>= 1) v += __shfl_xor(v, off, 16);
    return v;
}
// width-32 reductions over a 32-lane group
__device__ __forceinline__ float rmax32(float v) {
    #pragma unroll
    for (int off = 16; off; off >>= 1) v = fmaxf(v, __shfl_xor(v, off, 32));
    return v;
}
__device__ __forceinline__ float rsum32(float v) {
    #pragma unroll
    for (int off = 16; off; off >>= 1) v += __shfl_xor(v, off, 32);
    return v;
}

// One block per batch row b. 512 threads = 8 waves.
__global__ __launch_bounds__(NT)
void ens_main(const float* __restrict__ y, const int* __restrict__ labels,
              float* __restrict__ out, float* __restrict__ partial, int B)
{
    const int b   = blockIdx.x;
    const int tid = threadIdx.x;

    __shared__ float sl[MC + 64];     // logits tile (+pad)
    __shared__ float sems[CC];        // ems_out
    __shared__ float s_truep[MM], s_epl[MM], s_mx[MM], s_tpp[MM];
    __shared__ float s_w[MM], s_pw[MM];
    __shared__ float s_red[NT/64];
    __shared__ float s_bmax;
    __shared__ int   s_need;
    __shared__ unsigned s_selmask;

    // ---- Phase 1: global -> LDS, vectorized float4 (5520 % 4 == 0)
    {
        const float4* src = reinterpret_cast<const float4*>(y + (size_t)b * MC);
        float4* dst = reinterpret_cast<float4*>(sl);
        for (int i = tid; i < MC/4; i += NT) dst[i] = src[i];
    }
    __syncthreads();

    const int label = labels[b];

    // ---- Phase 2 (fast): per-m softmax stats, 32 lanes per m, register-cached.
    // mx is exp-free and order-independent -> bit-identical to round-1 max.
    {
        const int m = tid >> 5;
        const int l = tid & 31;
        const float* row = sl + m * CC;
        float v[11];
        float mx = -INFINITY;
        #pragma unroll
        for (int k = 0; k < 11; ++k) {
            const int c = l + (k << 5);
            if (c < CC) { v[k] = row[c]; mx = fmaxf(mx, v[k]); }
            else          v[k] = 0.f;
        }
        mx = rmax32(mx);
        float se = 0.f;
        #pragma unroll
        for (int k = 0; k < 11; ++k) {
            const int c = l + (k << 5);
            if (c < CC) se += fexp(v[k] - mx);
        }
        se = rsum32(se);
        if (l == 0) {
            const float lt = row[label];
            s_mx[m]    = mx;                          // exact max, reused by 3b
            s_truep[m] = fexp(lt - mx) / se;          // fast probs[b,m,label]
            s_epl[m]   = -(lt - mx - flog(se));       // -log_softmax[b,m,label]
        }
    }
    __syncthreads();

    // ---- Phase 3a: fast per-b math + top-4 by rank, lanes 0..15 (one per m)
    float tc = 0.f, wm = 0.f;
    bool  sel = false;
    if (tid < MM) {
        const int l = tid;
        const float tp = s_truep[l];
        const float mx = rmax16(tp);
        const float e  = fexp(tp - mx);
        tc = e / rsum16(e);
        const float s1 = fmaxf(rsum16(fabsf(tc)), 1e-12f);
        wm = tc / s1;
        int rank = 0;
        #pragma unroll
        for (int j = 0; j < MM; ++j) {
            const float vj = __shfl(tc, j, 16);
            rank += (vj > tc) || (vj == tc && j < l);
        }
        sel = (rank < KTOP);
        // Boundary-gap guard (see GAP_THR comment above)
        const float val4 = rmin16(sel ? tc : INFINITY);    // smallest selected
        const float val5 = rmax16(sel ? -INFINITY : tc);   // largest unselected
        if (l == 0) s_need = (val4 - val5 < GAP_THR) ? 1 : 0;
    }
    __syncthreads();

    // ---- Phase 3b: guarded rows -> selection via BIT-EXACT round-1 chain:
    // libm expf, strided-16 sum + xor-tree, then serial m-ascending tc +
    // 4x argmax on tid 0. (Verbatim from the passing round-5 kernel.)
    if (s_need) {
        if (tid < 256) {
            const int m = tid >> 4;
            const int l = tid & 15;
            const float* row = sl + m * CC;
            const float mx = s_mx[m];
            float se = 0.f;
            for (int c = l; c < CC; c += 16) se += expf(row[c] - mx);
            se = rsum16(se);
            if (l == 0) s_tpp[m] = expf(row[label] - mx) / se;
        }
        __syncthreads();
        if (tid == 0) {
            float tcp[MM];
            float mxx = -INFINITY;
            for (int m = 0; m < MM; ++m) mxx = fmaxf(mxx, s_tpp[m]);
            float ses = 0.f;
            for (int m = 0; m < MM; ++m) { tcp[m] = expf(s_tpp[m] - mxx); ses += tcp[m]; }
            for (int m = 0; m < MM; ++m) tcp[m] /= ses;
            bool used[MM];
            for (int m = 0; m < MM; ++m) used[m] = false;
            unsigned msk = 0;
            for (int k = 0; k < KTOP; ++k) {
                int bi = -1; float bv = -INFINITY;
                for (int m = 0; m < MM; ++m)
                    if (!used[m] && tcp[m] > bv) { bv = tcp[m]; bi = m; }
                used[bi] = true; msk |= (1u << bi);
            }
            s_selmask = msk;
        }
        __syncthreads();
    }

    // ---- Phase 3c: finish per-b math, lanes 0..15
    if (tid < MM) {
        const int l = tid;
        const size_t off_wm = (size_t)B * CC + 3;
        const size_t off_tc = off_wm + (size_t)B * MM;

        if (s_need) sel = ((s_selmask >> l) & 1u) != 0;

        const float post = sel ? tc : 0.f;
        const float psum = fmaxf(rsum16(fabsf(post)), 1e-12f);
        const float pw   = post / psum;
        const float mw = rmax16(wm);
        const float ex = fexp(wm - mw);
        const float xv = ex / rsum16(ex);
        const float mt = rmax16(tc);
        const float et = fexp(tc - mt);
        const float tv = et / rsum16(et);
        const float childp = s_epl[l] * xv;
        const float confp  = fmaxf(xv, 0.f) - xv * tv + flog(1.f + fexp(-fabsf(xv)));
        const float childs = rsum16(childp);
        const float confs  = rsum16(confp);
        if (l == 0) {
            partial[(size_t)b * 3 + 0] = childs;
            partial[(size_t)b * 3 + 1] = confs;
        }
        s_w[l]  = wm;
        s_pw[l] = pw;
        out[off_wm + (size_t)b * MM + l] = xv;  // wm_soft
        out[off_tc + (size_t)b * MM + l] = tc;  // true_confs
    }
    __syncthreads();

    // ---- Phase 4+5 fused: ems_out / ems_out_post, then ensemble-loss stats
    // on the register-held ems value (no LDS re-read passes).
    {
        const int c = tid;
        const bool act = (c < CC);
        float a = -INFINITY;
        if (act) {
            float aa = 0.f, ap = 0.f;
            #pragma unroll
            for (int m = 0; m < MM; ++m) {
                const float vv = sl[m * CC + c];
                aa = fmaf(vv, s_w[m],  aa);
                ap = fmaf(vv, s_pw[m], ap);
            }
            sems[c] = aa;                      // only needed for sems[label]
            out[(size_t)b * CC + c] = ap;      // ems_out_post
            a = aa;
        }
        // block max
        float mx = a;
        #pragma unroll
        for (int off = 32; off; off >>= 1) mx = fmaxf(mx, __shfl_xor(mx, off));
        if ((tid & 63) == 0) s_red[tid >> 6] = mx;
        __syncthreads();
        if (tid == 0) {
            float m2 = s_red[0];
            #pragma unroll
            for (int w = 1; w < NT/64; ++w) m2 = fmaxf(m2, s_red[w]);
            s_bmax = m2;
        }
        __syncthreads();
        mx = s_bmax;
        float e = act ? fexp(a - mx) : 0.f;
        #pragma unroll
        for (int off = 32; off; off >>= 1) e += __shfl_xor(e, off);
        if ((tid & 63) == 0) s_red[tid >> 6] = e;
        __syncthreads();
        if (tid == 0) {
            float s = 0.f;
            #pragma unroll
            for (int w = 0; w < NT/64; ++w) s += s_red[w];
            partial[(size_t)b * 3 + 2] = -(sems[label] - mx - flog(s));
        }
    }
}

// Deterministic fixed-order reduction of per-b partials -> the 3 scalar losses.
__global__ __launch_bounds__(256)
void ens_reduce(const float* __restrict__ partial, float* __restrict__ out, int B)
{
    const int tid = threadIdx.x;
    double c = 0.0, f = 0.0, e = 0.0;
    for (int i = tid; i < B; i += 256) {
        c += (double)partial[(size_t)i * 3 + 0];
        f += (double)partial[(size_t)i * 3 + 1];
        e += (double)partial[(size_t)i * 3 + 2];
    }
    #pragma unroll
    for (int off = 32; off; off >>= 1) {
        c += __shfl_xor(c, off);
        f += __shfl_xor(f, off);
        e += __shfl_xor(e, off);
    }
    __shared__ double rc[4], rf[4], re[4];
    if ((tid & 63) == 0) { rc[tid >> 6] = c; rf[tid >> 6] = f; re[tid >> 6] = e; }
    __syncthreads();
    if (tid == 0) {
        const double cs = rc[0] + rc[1] + rc[2] + rc[3];
        const double fs = rf[0] + rf[1] + rf[2] + rf[3];
        const double es = re[0] + re[1] + re[2] + re[3];
        const size_t base = (size_t)B * CC;
        out[base + 0] = (float)(cs / (double)((size_t)B * MM));  // child_loss
        out[base + 1] = (float)(fs / (double)((size_t)B * MM));  // confidence_loss
        out[base + 2] = (float)(es / (double)B);                 // ensemble_loss
    }
}

extern "C" void kernel_launch(void* const* d_in, const int* in_sizes, int n_in,
                              void* d_out, int out_size, void* d_ws, size_t ws_size,
                              hipStream_t stream)
{
    const float* y      = (const float*)d_in[0];
    const int*   labels = (const int*)d_in[1];
    const int    B      = in_sizes[1];      // 8192
    float* out     = (float*)d_out;
    float* partial = (float*)d_ws;          // B*3 floats = 96 KB

    ens_main<<<dim3(B), dim3(NT), 0, stream>>>(y, labels, out, partial, B);
    ens_reduce<<<dim3(1), dim3(256), 0, stream>>>(partial, out, B);
}